// Round 5
// baseline (857.962 us; speedup 1.0000x reference)
//
#include <hip/hip_runtime.h>
#include <hip/hip_bf16.h>

#define NN 4096

typedef unsigned short u16;
using bf16x8 = __attribute__((ext_vector_type(8))) short;
using f32x4  = __attribute__((ext_vector_type(4))) float;

// round-to-nearest-even f32 -> bf16 bits
__device__ inline u16 f2bf(float f) {
    union { float f; unsigned u; } c; c.f = f;
    unsigned r = (c.u + 0x7fffu + ((c.u >> 16) & 1u)) >> 16;
    return (u16)r;
}
__device__ inline float bf2f(u16 b) {
    union { unsigned u; float f; } c; c.u = ((unsigned)b) << 16;
    return c.f;
}

__device__ inline void gld16(const void* g, void* l) {
    __builtin_amdgcn_global_load_lds(
        (const __attribute__((address_space(1))) void*)g,
        (__attribute__((address_space(3))) void*)l, 16, 0, 0);
}

// ---------------- f32 -> bf16 convert ----------------
__global__ __launch_bounds__(256) void cvt_bf16(const float* __restrict__ s,
                                                u16* __restrict__ d) {
    size_t i = ((size_t)blockIdx.x * 256 + threadIdx.x) * 8;
    float4 v0 = *(const float4*)(s + i);
    float4 v1 = *(const float4*)(s + i + 4);
    bf16x8 o;
    o[0] = (short)f2bf(v0.x); o[1] = (short)f2bf(v0.y);
    o[2] = (short)f2bf(v0.z); o[3] = (short)f2bf(v0.w);
    o[4] = (short)f2bf(v1.x); o[5] = (short)f2bf(v1.y);
    o[6] = (short)f2bf(v1.z); o[7] = (short)f2bf(v1.w);
    *(bf16x8*)(d + i) = o;
}

// ---------------- transpose + convert: d[m][k] = bf16(s[k][m]) ----------------
__global__ __launch_bounds__(256) void tr_cvt(const float* __restrict__ s,
                                              u16* __restrict__ d) {
    __shared__ float t[32][33];
    int x  = blockIdx.x * 32 + threadIdx.x;
    int y0 = blockIdx.y * 32;
#pragma unroll
    for (int j = 0; j < 32; j += 8)
        t[threadIdx.y + j][threadIdx.x] = s[(size_t)(y0 + threadIdx.y + j) * NN + x];
    __syncthreads();
    int x2 = blockIdx.y * 32 + threadIdx.x;
    int y2 = blockIdx.x * 32;
#pragma unroll
    for (int j = 0; j < 32; j += 8)
        d[(size_t)(y2 + threadIdx.y + j) * NN + x2] = f2bf(t[threadIdx.x][threadIdx.y + j]);
}

// ---------------- bf16 elementwise sum: d = a + b ----------------
__global__ __launch_bounds__(256) void presum(const u16* __restrict__ a,
                                              const u16* __restrict__ b,
                                              u16* __restrict__ d) {
    size_t i = ((size_t)blockIdx.x * 256 + threadIdx.x) * 8;
    bf16x8 va = *(const bf16x8*)(a + i);
    bf16x8 vb = *(const bf16x8*)(b + i);
    bf16x8 o;
#pragma unroll
    for (int j = 0; j < 8; j++)
        o[j] = (short)f2bf(bf2f((u16)va[j]) + bf2f((u16)vb[j]));
    *(bf16x8*)(d + i) = o;
}

// ---------------- Karatsuba combine (in place on out) ----------------
// outL holds M1, outR holds M3, M2 in ws.  Cr = M1-M2 ; Ci = M3-M1-M2.
__global__ __launch_bounds__(256) void combine(float* __restrict__ out,
                                               const float* __restrict__ M2) {
    size_t i = ((size_t)blockIdx.x * 256 + threadIdx.x) * 4;  // elem in 4096x4096
    size_t m = i >> 12, n = i & 4095;
    float4 v1 = *(float4*)(out + m * 8192 + n);
    float4 v3 = *(float4*)(out + m * 8192 + 4096 + n);
    float4 v2 = *(const float4*)(M2 + m * 4096 + n);
    float4 cr, ci;
    cr.x = v1.x - v2.x; ci.x = v3.x - v1.x - v2.x;
    cr.y = v1.y - v2.y; ci.y = v3.y - v1.y - v2.y;
    cr.z = v1.z - v2.z; ci.z = v3.z - v1.z - v2.z;
    cr.w = v1.w - v2.w; ci.w = v3.w - v1.w - v2.w;
    *(float4*)(out + m * 8192 + n) = cr;
    *(float4*)(out + m * 8192 + 4096 + n) = ci;
}

// ================= 256x256-tile 8-phase NT GEMM (m201-style template) =========
// C[i][j] = sum_k A[i][k]*B[j][k]; A,B bf16 [4096][4096].
// 512 thr = 8 waves (2M x 4N), wave tile 128x64, BK=64, 2 K-tiles/iter.
// LDS 128 KB: sA/sB [2buf][2half][128x64]. Counted vmcnt(8); per-phase raw
// barriers + lgkmcnt(0) + setprio MFMA cluster (T3+T4+T5).
// LDS swizzle: 16B-block pb at row r holds K-block pb^(r&7); staged via
// inverse-permuted global source (gld_lds dest linear, rule #21).

#define MFMA16(a_, b_, c_) c_ = __builtin_amdgcn_mfma_f32_16x16x32_bf16(a_, b_, c_, 0, 0, 0)

#define LDA_(c, fr, ks) (*(const bf16x8*)&sA[c][wr][((fr)*16 + rl)*64 + ((((ks)*4 + kq) ^ rl7) * 8)])
#define LDB_(c, fc, ks) (*(const bf16x8*)&sB[c][bh][(bro + (fc)*16 + rl)*64 + ((((ks)*4 + kq) ^ rl7) * 8)])

#define LOADB(c) \
    b00 = LDB_(c,0,0); b01 = LDB_(c,0,1); b10 = LDB_(c,1,0); b11 = LDB_(c,1,1); \
    b20 = LDB_(c,2,0); b21 = LDB_(c,2,1); b30 = LDB_(c,3,0); b31 = LDB_(c,3,1);

#define PHASE(c, p, EXTRA) do { \
    bf16x8 a00 = LDA_(c, 2*(p), 0),   a01 = LDA_(c, 2*(p), 1); \
    bf16x8 a10 = LDA_(c, 2*(p)+1, 0), a11 = LDA_(c, 2*(p)+1, 1); \
    EXTRA \
    __builtin_amdgcn_s_barrier(); \
    asm volatile("s_waitcnt lgkmcnt(0)" ::: "memory"); \
    __builtin_amdgcn_sched_barrier(0); \
    __builtin_amdgcn_s_setprio(1); \
    MFMA16(a00, b00, acc[2*(p)][0]);   MFMA16(a01, b01, acc[2*(p)][0]); \
    MFMA16(a00, b10, acc[2*(p)][1]);   MFMA16(a01, b11, acc[2*(p)][1]); \
    MFMA16(a00, b20, acc[2*(p)][2]);   MFMA16(a01, b21, acc[2*(p)][2]); \
    MFMA16(a00, b30, acc[2*(p)][3]);   MFMA16(a01, b31, acc[2*(p)][3]); \
    MFMA16(a10, b00, acc[2*(p)+1][0]); MFMA16(a11, b01, acc[2*(p)+1][0]); \
    MFMA16(a10, b10, acc[2*(p)+1][1]); MFMA16(a11, b11, acc[2*(p)+1][1]); \
    MFMA16(a10, b20, acc[2*(p)+1][2]); MFMA16(a11, b21, acc[2*(p)+1][2]); \
    MFMA16(a10, b30, acc[2*(p)+1][3]); MFMA16(a11, b31, acc[2*(p)+1][3]); \
    __builtin_amdgcn_s_setprio(0); \
    __builtin_amdgcn_s_barrier(); \
} while (0)

#define SG(c, kk) do { \
    gld16(A  + aBase + (size_t)(kk),              &sA[c][0][tds]); \
    gld16(A  + aBase + (size_t)(kk) +  64*4096,   &sA[c][0][4096 + tds]); \
    gld16(A  + aBase + (size_t)(kk) + 128*4096,   &sA[c][1][tds]); \
    gld16(A  + aBase + (size_t)(kk) + 192*4096,   &sA[c][1][4096 + tds]); \
    gld16(Bp + bBase + (size_t)(kk),              &sB[c][0][tds]); \
    gld16(Bp + bBase + (size_t)(kk) +  64*4096,   &sB[c][0][4096 + tds]); \
    gld16(Bp + bBase + (size_t)(kk) + 128*4096,   &sB[c][1][tds]); \
    gld16(Bp + bBase + (size_t)(kk) + 192*4096,   &sB[c][1][4096 + tds]); \
} while (0)

#define KTILE(c, Tn) do { \
    PHASE(c, 0, LOADB(c)); \
    PHASE(c, 1, ); \
    PHASE(c, 2, ); \
    PHASE(c, 3, ); \
    if ((Tn) < 64) { SG(c, (Tn)*64); asm volatile("s_waitcnt vmcnt(8)" ::: "memory"); } \
    else           { asm volatile("s_waitcnt vmcnt(0)" ::: "memory"); } \
    __builtin_amdgcn_s_barrier(); \
    __builtin_amdgcn_sched_barrier(0); \
} while (0)

template <bool F32OUT>
__global__ __launch_bounds__(512, 2) void gemm256(
    const u16* __restrict__ A, const u16* __restrict__ Bp,
    u16* __restrict__ Cb, float* __restrict__ Cf, int cstride) {
    __shared__ u16 sA[2][2][8192];   // [buf][half][128*64]
    __shared__ u16 sB[2][2][8192];

    // bijective XCD-region swizzle: 256 blocks -> 16x16 tiles, 8 regions 4x8
    const int bid = blockIdx.x;
    const int rr = (bid & 7) >> 1, rc = bid & 1;
    const int local = bid >> 3;
    const int brow = (rr * 4 + (local >> 3)) * 256;
    const int bcol = (rc * 8 + (local & 7)) * 256;

    const int t    = threadIdx.x;
    const int lane = t & 63;
    const int wid  = t >> 6;
    const int wr   = wid >> 2;        // 0..1  A half
    const int wc   = wid & 3;         // 0..3
    const int bh   = wc >> 1;         // B half
    const int bro  = (wc & 1) * 64;   // B row offset in half
    const int rl   = lane & 15;
    const int kq   = lane >> 4;       // 0..3
    const int rl7  = rl & 7;

    // staging map: thread t covers row r0s = t>>3 (of each 64-row quarter),
    // 16B-block pbs = t&7; fetches global K-block pbs^(r0s&7) (inverse swizzle)
    const int r0s = t >> 3;
    const int cbs = (t & 7) ^ (r0s & 7);
    const int tds = t * 8;            // u16 LDS offset (lane*16B within wave)
    const size_t aBase = (size_t)(brow + r0s) * NN + cbs * 8;
    const size_t bBase = (size_t)(bcol + r0s) * NN + cbs * 8;

    f32x4 acc[8][4] = {};
    bf16x8 b00, b01, b10, b11, b20, b21, b30, b31;

    SG(0, 0);
    SG(1, 64);
    asm volatile("s_waitcnt vmcnt(8)" ::: "memory");
    __builtin_amdgcn_s_barrier();
    __builtin_amdgcn_sched_barrier(0);

    for (int i = 0; i < 32; ++i) {
        KTILE(0, 2 * i + 2);
        KTILE(1, 2 * i + 3);
    }

    // epilogue: C/D layout col=lane&15, row=kq*4+reg
    const int rg = kq * 4;
#pragma unroll
    for (int fr = 0; fr < 8; fr++)
#pragma unroll
        for (int fc = 0; fc < 4; fc++) {
            const int col = bcol + wc * 64 + fc * 16 + rl;
#pragma unroll
            for (int e = 0; e < 4; e++) {
                const int row = brow + wr * 128 + fr * 16 + rg + e;
                if (F32OUT)
                    Cf[(size_t)row * cstride + col] = acc[fr][fc][e];
                else
                    Cb[(size_t)row * NN + col] = f2bf(acc[fr][fc][e]);
            }
        }
}

extern "C" void kernel_launch(void* const* d_in, const int* in_sizes, int n_in,
                              void* d_out, int out_size, void* d_ws, size_t ws_size,
                              hipStream_t stream) {
    const float* x  = (const float*)d_in[0];
    const float* Wr = (const float*)d_in[1];
    const float* Wi = (const float*)d_in[2];
    float* out = (float*)d_out;

    const size_t SZ = (size_t)NN * NN;
    u16* ws = (u16*)d_ws;
    u16* s0 = ws;            // xb   -> WrT
    u16* s1 = ws + SZ;       // Wrb  -> WiT
    u16* s2 = ws + 2 * SZ;   // Wib  -> S_A ; later (s2,s3) = M2 f32
    u16* s3 = ws + 3 * SZ;   // Rtr
    u16* s4 = ws + 4 * SZ;   // Rti
    u16* s5 = ws + 5 * SZ;   // S_B
    float* M2 = (float*)s2;  // 64MB f32 over s2+s3 (dead by then)

    // 1) convert inputs to bf16
    cvt_bf16<<<8192, 256, 0, stream>>>(x,  s0);
    cvt_bf16<<<8192, 256, 0, stream>>>(Wr, s1);
    cvt_bf16<<<8192, 256, 0, stream>>>(Wi, s2);

    // 2) pass 1: Rtr = NT(Wr, x), Rti = NT(Wi, x)   (bf16 out)
    gemm256<false><<<256, 512, 0, stream>>>(s1, s0, s3, nullptr, 0);
    gemm256<false><<<256, 512, 0, stream>>>(s2, s0, s4, nullptr, 0);

    // 3) transposed weights (s0,s1 dead), Karatsuba presums
    tr_cvt<<<dim3(128, 128), dim3(32, 8), 0, stream>>>(Wr, s0);   // WrT
    tr_cvt<<<dim3(128, 128), dim3(32, 8), 0, stream>>>(Wi, s1);   // WiT
    presum<<<8192, 256, 0, stream>>>(s0, s1, s2);                 // S_A = WrT+WiT
    presum<<<8192, 256, 0, stream>>>(s3, s4, s5);                 // S_B = Rtr+Rti

    // 4) pass 2 via Karatsuba: M3 -> outR, M1 -> outL, M2 -> ws (order matters
    //    for slot reuse: M2 overwrites s2(S_A)/s3(Rtr) after their last reads)
    gemm256<true><<<256, 512, 0, stream>>>(s2, s5, nullptr, out + NN, 2 * NN); // M3
    gemm256<true><<<256, 512, 0, stream>>>(s0, s3, nullptr, out,      2 * NN); // M1
    gemm256<true><<<256, 512, 0, stream>>>(s1, s4, nullptr, M2,       NN);     // M2

    // 5) combine: Cr = M1-M2, Ci = M3-M1-M2  (in place on out)
    combine<<<16384, 256, 0, stream>>>(out, M2);
}

// Round 6
// 770.290 us; speedup vs baseline: 1.1138x; 1.1138x over previous
//
#include <hip/hip_runtime.h>
#include <hip/hip_bf16.h>

#define NN 4096

typedef unsigned short u16;
using bf16x8 = __attribute__((ext_vector_type(8))) short;
using f32x4  = __attribute__((ext_vector_type(4))) float;
using u32x4  = __attribute__((ext_vector_type(4))) unsigned int;

// round-to-nearest-even f32 -> bf16 bits
__device__ inline u16 f2bf(float f) {
    union { float f; unsigned u; } c; c.f = f;
    unsigned r = (c.u + 0x7fffu + ((c.u >> 16) & 1u)) >> 16;
    return (u16)r;
}

__device__ inline void gld16(const void* g, void* l) {
    __builtin_amdgcn_global_load_lds(
        (const __attribute__((address_space(1))) void*)g,
        (__attribute__((address_space(3))) void*)l, 16, 0, 0);
}

__device__ inline bf16x8 negbf(bf16x8 v) {
    u32x4 u; __builtin_memcpy(&u, &v, 16);
    u ^= 0x80008000u;
    bf16x8 r; __builtin_memcpy(&r, &u, 16);
    return r;
}

// Bijective XCD-region block swizzle (kept from R4; neutral on time).
__device__ inline void swz_tile(int bid, int& brow, int& bcol) {
    const int xcd   = bid & 7;
    const int local = bid >> 3;
    const int rr    = xcd >> 1;
    const int rc    = xcd & 1;
    brow = (rr * 8  + (local >> 4)) * 128;
    bcol = (rc * 16 + (local & 15)) * 128;
}

// ---------------- f32 -> bf16 convert ----------------
__global__ __launch_bounds__(256) void cvt_bf16(const float* __restrict__ s,
                                                u16* __restrict__ d) {
    size_t i = ((size_t)blockIdx.x * 256 + threadIdx.x) * 8;
    float4 v0 = *(const float4*)(s + i);
    float4 v1 = *(const float4*)(s + i + 4);
    bf16x8 o;
    o[0] = (short)f2bf(v0.x); o[1] = (short)f2bf(v0.y);
    o[2] = (short)f2bf(v0.z); o[3] = (short)f2bf(v0.w);
    o[4] = (short)f2bf(v1.x); o[5] = (short)f2bf(v1.y);
    o[6] = (short)f2bf(v1.z); o[7] = (short)f2bf(v1.w);
    *(bf16x8*)(d + i) = o;
}

// ---------------- transpose + convert: d[m][k] = bf16(s[k][m]) ----------------
__global__ __launch_bounds__(256) void tr_cvt(const float* __restrict__ s,
                                              u16* __restrict__ d) {
    __shared__ float t[32][33];
    int x  = blockIdx.x * 32 + threadIdx.x;
    int y0 = blockIdx.y * 32;
#pragma unroll
    for (int j = 0; j < 32; j += 8)
        t[threadIdx.y + j][threadIdx.x] = s[(size_t)(y0 + threadIdx.y + j) * NN + x];
    __syncthreads();
    int x2 = blockIdx.y * 32 + threadIdx.x;
    int y2 = blockIdx.x * 32;
#pragma unroll
    for (int j = 0; j < 32; j += 8)
        d[(size_t)(y2 + threadIdx.y + j) * NN + x2] = f2bf(t[threadIdx.x][threadIdx.y + j]);
}

// ---- phase primitives (rule #18: sched_barrier after inline waitcnt) ----
#define P_BAR  __builtin_amdgcn_s_barrier()
#define P_LGKM do { asm volatile("s_waitcnt lgkmcnt(0)" ::: "memory"); \
                    __builtin_amdgcn_sched_barrier(0); } while (0)
#define P_VM0  do { asm volatile("s_waitcnt vmcnt(0)" ::: "memory"); \
                    __builtin_amdgcn_sched_barrier(0); } while (0)

#define CHAIN(AF, BF, ACC) do { \
    __builtin_amdgcn_s_setprio(1); \
    _Pragma("unroll") \
    for (int i_ = 0; i_ < 4; i_++) \
        _Pragma("unroll") \
        for (int j_ = 0; j_ < 4; j_++) \
            ACC[i_][j_] = __builtin_amdgcn_mfma_f32_16x16x32_bf16(AF[i_], BF[j_], ACC[i_][j_], 0, 0, 0); \
    __builtin_amdgcn_s_setprio(0); \
} while (0)

// read 4 fragments from sm[cc][TILE], rows BASE+{0,16,32,48}+rl
#define RD4(DST, CC, TILE, BASE) do { \
    _Pragma("unroll") \
    for (int i_ = 0; i_ < 4; i_++) \
        DST[i_] = *(const bf16x8*)&sm[CC][TILE][((BASE) + i_ * 16 + rl) * 32 + kg]; \
} while (0)

// LDS swizzle (both GEMMs): physical 16B-block p at row r holds logical block
// p ^ ((r>>1)&3); staged via inverse-permuted GLOBAL source (gld_lds dest
// linear, rule #21); read back with same XOR. Conflict-free (R3: 3.35e7->0).

// ---------------- pass 1 (FUSED, 2-phase K-step): Rtr=NT(Wr,x), Rti=NT(Wi,x) --
__global__ __launch_bounds__(256, 2) void gemm_pass1(
    const u16* __restrict__ Ar, const u16* __restrict__ Ai,
    const u16* __restrict__ B,
    u16* __restrict__ Cr, u16* __restrict__ Ci) {
    __shared__ u16 sm[2][3][4096];   // [buf][Wr,Wi,x] = 48 KB

    int brow, bcol;
    swz_tile(blockIdx.x, brow, bcol);

    const int tid  = threadIdx.x;
    const int lane = tid & 63;
    const int wid  = tid >> 6;
    const int wm   = (wid >> 1) * 64;
    const int wn   = (wid & 1) * 64;

    f32x4 accr[4][4] = {};
    f32x4 acci[4][4] = {};

    const int r0 = tid >> 2;
    const int lb = (tid & 3) ^ ((r0 >> 1) & 3);
    const size_t aoff0 = (size_t)(brow + r0) * NN + lb * 8;
    const size_t aoff1 = aoff0 + (size_t)64 * NN;
    const size_t boff0 = (size_t)(bcol + r0) * NN + lb * 8;
    const size_t boff1 = boff0 + (size_t)64 * NN;
    const int rl = lane & 15;
    const int kg = ((lane >> 4) ^ ((rl >> 1) & 3)) * 8;

#define T0(b, kk) gld16(Ar + aoff0 + (kk), &sm[b][0][tid * 8])
#define T1(b, kk) gld16(Ar + aoff1 + (kk), &sm[b][0][2048 + tid * 8])
#define T2(b, kk) gld16(Ai + aoff0 + (kk), &sm[b][1][tid * 8])
#define T3(b, kk) gld16(Ai + aoff1 + (kk), &sm[b][1][2048 + tid * 8])
#define T4(b, kk) gld16(B  + boff0 + (kk), &sm[b][2][tid * 8])
#define T5(b, kk) gld16(B  + boff1 + (kk), &sm[b][2][2048 + tid * 8])

#define KSTEP1(CC, NB, KN, DOSTG) do { \
    bf16x8 af[4], ag[4], bb[4]; \
    RD4(af, CC, 0, wm); RD4(bb, CC, 2, wn); \
    if (DOSTG) { T0(NB, KN); T1(NB, KN); T2(NB, KN); T3(NB, KN); } \
    P_BAR; P_LGKM; \
    CHAIN(af, bb, accr); \
    P_BAR; \
    RD4(ag, CC, 1, wm); \
    if (DOSTG) { T4(NB, KN); T5(NB, KN); } \
    P_BAR; P_LGKM; \
    CHAIN(ag, bb, acci); \
    if (DOSTG) P_VM0; \
    P_BAR; \
} while (0)

    T0(0, 0); T1(0, 0); T2(0, 0); T3(0, 0); T4(0, 0); T5(0, 0);
    P_VM0;
    P_BAR;
    for (int t = 0; t < NN / 32 - 1; ++t) {
        const int cc = t & 1, nb = cc ^ 1;
        KSTEP1(cc, nb, (size_t)(t + 1) * 32, 1);
    }
    KSTEP1(1, 0, 0, 0);

    const int rg = (lane >> 4) * 4;
#pragma unroll
    for (int i = 0; i < 4; i++)
#pragma unroll
        for (int j = 0; j < 4; j++) {
            int col = bcol + wn + j * 16 + rl;
#pragma unroll
            for (int r = 0; r < 4; r++) {
                int row = brow + wm + i * 16 + rg + r;
                Cr[(size_t)row * NN + col] = f2bf(accr[i][j][r]);
                Ci[(size_t)row * NN + col] = f2bf(acci[i][j][r]);
            }
        }
}

// ------- pass 2 (FUSED dual complex, 4-phase K-step = 4 product chains) -------
// C_r[m,n] = sum_k Ar[m,k]Br[n,k] - Ai[m,k]Bi[n,k]
// C_i[m,n] = sum_k Ar[m,k]Bi[n,k] + Ai[m,k]Br[n,k]
__global__ __launch_bounds__(256, 2) void gemm_pass2(
    const u16* __restrict__ Ar, const u16* __restrict__ Ai,
    const u16* __restrict__ Br, const u16* __restrict__ Bi,
    float* __restrict__ Out) {
    __shared__ u16 sm[2][4][4096];   // [buf][Ar,Ai,Br,Bi] = 64 KB

    int brow, bcol;
    swz_tile(blockIdx.x, brow, bcol);

    const int tid  = threadIdx.x;
    const int lane = tid & 63;
    const int wid  = tid >> 6;
    const int wm   = (wid >> 1) * 64;
    const int wn   = (wid & 1) * 64;

    f32x4 accr[4][4] = {};
    f32x4 acci[4][4] = {};

    const int r0 = tid >> 2;
    const int lb = (tid & 3) ^ ((r0 >> 1) & 3);
    const size_t moff0 = (size_t)(brow + r0) * NN + lb * 8;
    const size_t moff1 = moff0 + (size_t)64 * NN;
    const size_t noff0 = (size_t)(bcol + r0) * NN + lb * 8;
    const size_t noff1 = noff0 + (size_t)64 * NN;
    const int rl = lane & 15;
    const int kg = ((lane >> 4) ^ ((rl >> 1) & 3)) * 8;

#define SL0(b, kk) gld16(Ar + moff0 + (kk), &sm[b][0][tid * 8])
#define SL1(b, kk) gld16(Ar + moff1 + (kk), &sm[b][0][2048 + tid * 8])
#define SL2(b, kk) gld16(Ai + moff0 + (kk), &sm[b][1][tid * 8])
#define SL3(b, kk) gld16(Ai + moff1 + (kk), &sm[b][1][2048 + tid * 8])
#define SL4(b, kk) gld16(Br + noff0 + (kk), &sm[b][2][tid * 8])
#define SL5(b, kk) gld16(Br + noff1 + (kk), &sm[b][2][2048 + tid * 8])
#define SL6(b, kk) gld16(Bi + noff0 + (kk), &sm[b][3][tid * 8])
#define SL7(b, kk) gld16(Bi + noff1 + (kk), &sm[b][3][2048 + tid * 8])

#define KSTEP2(CC, NB, KN, DOSTG) do { \
    bf16x8 ar[4], ai[4], br[4], bi[4]; \
    /* P0: acci += ar*bi */ \
    RD4(ar, CC, 0, wm); RD4(bi, CC, 3, wn); \
    if (DOSTG) { SL0(NB, KN); SL1(NB, KN); SL2(NB, KN); } \
    P_BAR; P_LGKM; \
    CHAIN(ar, bi, acci); \
    P_BAR; \
    /* P1: accr += ar*br */ \
    RD4(br, CC, 2, wn); \
    if (DOSTG) { SL3(NB, KN); SL4(NB, KN); SL5(NB, KN); } \
    P_BAR; P_LGKM; \
    CHAIN(ar, br, accr); \
    P_BAR; \
    /* P2: acci += ai*br */ \
    RD4(ai, CC, 1, wm); \
    if (DOSTG) { SL6(NB, KN); SL7(NB, KN); } \
    P_BAR; P_LGKM; \
    CHAIN(ai, br, acci); \
    P_BAR; \
    /* P3: accr += (-ai)*bi  (no reads, no pre-barrier) */ \
    _Pragma("unroll") for (int i_ = 0; i_ < 4; i_++) ai[i_] = negbf(ai[i_]); \
    CHAIN(ai, bi, accr); \
    if (DOSTG) P_VM0; \
    P_BAR; \
} while (0)

    SL0(0, 0); SL1(0, 0); SL2(0, 0); SL3(0, 0);
    SL4(0, 0); SL5(0, 0); SL6(0, 0); SL7(0, 0);
    P_VM0;
    P_BAR;
    for (int t = 0; t < NN / 32 - 1; ++t) {
        const int cc = t & 1, nb = cc ^ 1;
        KSTEP2(cc, nb, (size_t)(t + 1) * 32, 1);
    }
    KSTEP2(1, 0, 0, 0);

    const int rg = (lane >> 4) * 4;
#pragma unroll
    for (int i = 0; i < 4; i++)
#pragma unroll
        for (int j = 0; j < 4; j++) {
            int col = bcol + wn + j * 16 + rl;
#pragma unroll
            for (int r = 0; r < 4; r++) {
                int row = brow + wm + i * 16 + rg + r;
                Out[(size_t)row * (2 * NN) + col]      = accr[i][j][r];
                Out[(size_t)row * (2 * NN) + NN + col] = acci[i][j][r];
            }
        }
}

extern "C" void kernel_launch(void* const* d_in, const int* in_sizes, int n_in,
                              void* d_out, int out_size, void* d_ws, size_t ws_size,
                              hipStream_t stream) {
    const float* x  = (const float*)d_in[0];
    const float* Wr = (const float*)d_in[1];
    const float* Wi = (const float*)d_in[2];
    float* out = (float*)d_out;

    const size_t SZ = (size_t)NN * NN;
    u16* ws  = (u16*)d_ws;
    u16* xb  = ws;            // slot 0: bf16 x        (later reused: WrT)
    u16* Wrb = ws + SZ;       // slot 1: bf16 W_r      (later reused: WiT)
    u16* Wib = ws + 2 * SZ;   // slot 2: bf16 W_i
    u16* Rtr = ws + 3 * SZ;   // slot 3: R_r^T bf16
    u16* Rti = ws + 4 * SZ;   // slot 4: R_i^T bf16

    // 1) convert inputs to bf16
    cvt_bf16<<<8192, 256, 0, stream>>>(x,  xb);
    cvt_bf16<<<8192, 256, 0, stream>>>(Wr, Wrb);
    cvt_bf16<<<8192, 256, 0, stream>>>(Wi, Wib);

    // 2) fused pass 1: Rt_r = NT(W_r, x), Rt_i = NT(W_i, x)
    gemm_pass1<<<1024, 256, 0, stream>>>(Wrb, Wib, xb, Rtr, Rti);

    // 3) transposed bf16 weights (reuse slots 0,1)
    u16* WrT = xb;
    u16* WiT = Wrb;
    tr_cvt<<<dim3(128, 128), dim3(32, 8), 0, stream>>>(Wr, WrT);
    tr_cvt<<<dim3(128, 128), dim3(32, 8), 0, stream>>>(Wi, WiT);

    // 4) fused pass 2 -> d_out [NN][2*NN]
    gemm_pass2<<<1024, 256, 0, stream>>>(WrT, WiT, Rtr, Rti, out);
}